// Round 1
// baseline (547.628 us; speedup 1.0000x reference)
//
#include <hip/hip_runtime.h>
#include <hip/hip_bf16.h>

#define N_PTS 100000
#define KOFF 343
#define EPS 1e-5f

typedef __hip_bfloat16 bf16;
typedef __attribute__((ext_vector_type(4))) float f32x4;
typedef __attribute__((ext_vector_type(16))) float f32x16;
typedef __attribute__((ext_vector_type(8))) short s16x8;

// ---------------- pack: w_conv [343][32][32] f32 -> bf16 B-fragments ----------------
// wpk layout: [k][s][lane][j], element = w_conv[k][s*16 + (lane>>5)*8 + j][lane&31]
__global__ __launch_bounds__(256) void pack_kernel(const float* __restrict__ w_conv,
                                                   bf16* __restrict__ wpk) {
  int t = blockIdx.x * 256 + threadIdx.x;
  if (t >= KOFF * 128) return;
  int l = t & 63;
  int s = (t >> 6) & 1;
  int k = t >> 7;
  int col = l & 31;
  int kq = l >> 5;
  const float* wk = w_conv + k * 1024;
  s16x8 v;
  for (int j = 0; j < 8; ++j) {
    bf16 h = __float2bfloat16(wk[(s * 16 + kq * 8 + j) * 32 + col]);
    short sv;
    __builtin_memcpy(&sv, &h, 2);
    v[j] = sv;
  }
  *reinterpret_cast<s16x8*>(reinterpret_cast<char*>(wpk) + (size_t)t * 16) = v;
}

// ---------------- unary1: h1b = bf16( LN(feats @ w1) )  [N,32] ----------------
__global__ __launch_bounds__(256) void unary1_kernel(const float* __restrict__ feats,
    const float* __restrict__ w1, const float* __restrict__ g1,
    const float* __restrict__ b1, bf16* __restrict__ h1b) {
  __shared__ float sf[8][128];
  __shared__ float sw[128 * 32];
  int tid = threadIdx.x;
  int rbase = blockIdx.x * 8;
  // stage w1 (16 KB)
  for (int i = tid; i < 1024; i += 256)
    reinterpret_cast<f32x4*>(sw)[i] = reinterpret_cast<const f32x4*>(w1)[i];
  // stage 8 feats rows (4 KB)
  {
    int i = tid;                      // 256 f32x4 = 8 rows * 32
    int r = rbase + (i >> 5);
    f32x4 v = {0.f, 0.f, 0.f, 0.f};
    if (r < N_PTS) v = reinterpret_cast<const f32x4*>(feats)[(size_t)r * 32 + (i & 31)];
    reinterpret_cast<f32x4*>(&sf[0][0])[i] = v;
  }
  __syncthreads();
  int half = tid >> 5;                // row within block (0..7)
  int c = tid & 31;                   // channel
  int r = rbase + half;
  const float* frow = sf[half];
  float acc = 0.f;
  #pragma unroll 8
  for (int kk = 0; kk < 128; ++kk)
    acc += frow[kk] * sw[kk * 32 + c];
  // LN over the 32 channels (lanes within each 32-lane group)
  float s = acc, s2 = acc * acc;
  #pragma unroll
  for (int m = 16; m >= 1; m >>= 1) {
    s  += __shfl_xor(s,  m, 64);
    s2 += __shfl_xor(s2, m, 64);
  }
  float mean = s * (1.f / 32.f);
  float var  = s2 * (1.f / 32.f) - mean * mean;
  float y = (acc - mean) * rsqrtf(var + EPS) * g1[c] + b1[c];
  if (r < N_PTS) h1b[(size_t)r * 32 + c] = __float2bfloat16(y);
}

// ---------------- conv: h2 = sum_k gather(h1b, nbr[:,k]) @ w_conv[k]  [N,32] f32 ----------------
// wave handles 2 tiles of 32 points; A-frag: row = lane&31, k = (lane>>5)*8+j (+16 for s=1)
// D-frag: col = lane&31, row = (reg&3) + 8*(reg>>2) + 4*(lane>>5)   [verified m74/m101]
__global__ __launch_bounds__(128) void conv_kernel(const bf16* __restrict__ h1b,
    const int* __restrict__ nbr, const bf16* __restrict__ wpk,
    float* __restrict__ h2) {
  int tid = threadIdx.x;
  int wave = tid >> 6;
  int l = tid & 63;
  int col = l & 31;
  int kq = l >> 5;
  int pbase = blockIdx.x * 128 + wave * 64;
  int p0 = pbase + col;
  int p1 = pbase + 32 + col;
  bool v0 = p0 < N_PTS, v1 = p1 < N_PTS;
  const int* nrow0 = nbr + (size_t)p0 * KOFF;
  const int* nrow1 = nbr + (size_t)p1 * KOFF;
  f32x16 acc0, acc1;
  for (int i = 0; i < 16; ++i) { acc0[i] = 0.f; acc1[i] = 0.f; }
  const s16x8* wb = reinterpret_cast<const s16x8*>(wpk);
  const s16x8 zv = {0, 0, 0, 0, 0, 0, 0, 0};
  for (int k = 0; k < KOFF; ++k) {
    int idx0 = v0 ? nrow0[k] : -1;
    int idx1 = v1 ? nrow1[k] : -1;
    const s16x8* r0 = reinterpret_cast<const s16x8*>(h1b + (size_t)(idx0 < 0 ? 0 : idx0) * 32);
    const s16x8* r1 = reinterpret_cast<const s16x8*>(h1b + (size_t)(idx1 < 0 ? 0 : idx1) * 32);
    s16x8 a00 = r0[kq],     a01 = r0[2 + kq];
    s16x8 a10 = r1[kq],     a11 = r1[2 + kq];
    a00 = idx0 < 0 ? zv : a00;
    a01 = idx0 < 0 ? zv : a01;
    a10 = idx1 < 0 ? zv : a10;
    a11 = idx1 < 0 ? zv : a11;
    s16x8 b0 = wb[(size_t)k * 128 + l];
    s16x8 b1 = wb[(size_t)k * 128 + 64 + l];
    acc0 = __builtin_amdgcn_mfma_f32_32x32x16_bf16(a00, b0, acc0, 0, 0, 0);
    acc0 = __builtin_amdgcn_mfma_f32_32x32x16_bf16(a01, b1, acc0, 0, 0, 0);
    acc1 = __builtin_amdgcn_mfma_f32_32x32x16_bf16(a10, b0, acc1, 0, 0, 0);
    acc1 = __builtin_amdgcn_mfma_f32_32x32x16_bf16(a11, b1, acc1, 0, 0, 0);
  }
  #pragma unroll
  for (int reg = 0; reg < 16; ++reg) {
    int rrow = (reg & 3) + 8 * (reg >> 2) + 4 * kq;
    int row0 = pbase + rrow;
    int row1 = pbase + 32 + rrow;
    if (row0 < N_PTS) h2[(size_t)row0 * 32 + col] = acc0[reg];
    if (row1 < N_PTS) h2[(size_t)row1 * 32 + col] = acc1[reg];
  }
}

// ---------------- unary2: out = gelu(LN(h2 @ w2)) + feats  [N,128] f32 ----------------
__global__ __launch_bounds__(256) void unary2_kernel(const float* __restrict__ h2,
    const float* __restrict__ w2, const float* __restrict__ g2,
    const float* __restrict__ b2, const float* __restrict__ feats,
    float* __restrict__ out) {
  int tid = threadIdx.x;
  int wave = tid >> 6;
  int l = tid & 63;
  int r = blockIdx.x * 4 + wave;
  if (r >= N_PTS) return;
  const float* hrow = h2 + (size_t)r * 32;
  float acc0 = 0.f, acc1 = 0.f;
  #pragma unroll
  for (int q = 0; q < 8; ++q) {
    f32x4 hv = reinterpret_cast<const f32x4*>(hrow)[q];
    #pragma unroll
    for (int j = 0; j < 4; ++j) {
      int kk = q * 4 + j;
      float h = hv[j];
      acc0 += h * w2[kk * 128 + l];
      acc1 += h * w2[kk * 128 + 64 + l];
    }
  }
  float s = acc0 + acc1, s2 = acc0 * acc0 + acc1 * acc1;
  #pragma unroll
  for (int m = 32; m >= 1; m >>= 1) {
    s  += __shfl_xor(s,  m, 64);
    s2 += __shfl_xor(s2, m, 64);
  }
  float mean = s * (1.f / 128.f);
  float var  = s2 * (1.f / 128.f) - mean * mean;
  float inv = rsqrtf(var + EPS);
  float y0 = (acc0 - mean) * inv * g2[l] + b2[l];
  float y1 = (acc1 - mean) * inv * g2[64 + l] + b2[64 + l];
  float ge0 = 0.5f * y0 * (1.f + erff(y0 * 0.70710678118f));
  float ge1 = 0.5f * y1 * (1.f + erff(y1 * 0.70710678118f));
  out[(size_t)r * 128 + l]      = ge0 + feats[(size_t)r * 128 + l];
  out[(size_t)r * 128 + 64 + l] = ge1 + feats[(size_t)r * 128 + 64 + l];
}

extern "C" void kernel_launch(void* const* d_in, const int* in_sizes, int n_in,
                              void* d_out, int out_size, void* d_ws, size_t ws_size,
                              hipStream_t stream) {
  const float* feats  = (const float*)d_in[0];
  const int*   nbr    = (const int*)d_in[1];
  const float* w1     = (const float*)d_in[2];
  const float* ln1_g  = (const float*)d_in[3];
  const float* ln1_b  = (const float*)d_in[4];
  const float* w_conv = (const float*)d_in[5];
  const float* w2     = (const float*)d_in[6];
  const float* ln2_g  = (const float*)d_in[7];
  const float* ln2_b  = (const float*)d_in[8];
  float* out = (float*)d_out;
  char* ws = (char*)d_ws;
  bf16*  h1b = (bf16*)ws;                    // 100000*32*2  = 6,400,000 B
  bf16*  wpk = (bf16*)(ws + 6400000);        // 343*128*16   =   702,464 B
  float* h2  = (float*)(ws + 7102464);       // 100000*32*4  = 12,800,000 B

  hipLaunchKernelGGL(pack_kernel,   dim3((KOFF * 128 + 255) / 256), dim3(256), 0, stream, w_conv, wpk);
  hipLaunchKernelGGL(unary1_kernel, dim3((N_PTS + 7) / 8),          dim3(256), 0, stream, feats, w1, ln1_g, ln1_b, h1b);
  hipLaunchKernelGGL(conv_kernel,   dim3((N_PTS + 127) / 128),      dim3(128), 0, stream, h1b, nbr, wpk, h2);
  hipLaunchKernelGGL(unary2_kernel, dim3((N_PTS + 3) / 4),          dim3(256), 0, stream, h2, w2, ln2_g, ln2_b, feats, out);
}

// Round 2
// 507.025 us; speedup vs baseline: 1.0801x; 1.0801x over previous
//
#include <hip/hip_runtime.h>
#include <hip/hip_bf16.h>

#define N_PTS 100000
#define KOFF 343
#define EPS 1e-5f

typedef __hip_bfloat16 bf16;
typedef __attribute__((ext_vector_type(4))) float f32x4;
typedef __attribute__((ext_vector_type(16))) float f32x16;
typedef __attribute__((ext_vector_type(8))) short s16x8;

// ---------------- pack: w_conv [343][32][32] f32 -> bf16 B-fragments ----------------
// wpk layout: [k][s][lane][j], element = w_conv[k][s*16 + (lane>>5)*8 + j][lane&31]
__global__ __launch_bounds__(256) void pack_kernel(const float* __restrict__ w_conv,
                                                   bf16* __restrict__ wpk) {
  int t = blockIdx.x * 256 + threadIdx.x;
  if (t >= KOFF * 128) return;
  int l = t & 63;
  int s = (t >> 6) & 1;
  int k = t >> 7;
  int col = l & 31;
  int kq = l >> 5;
  const float* wk = w_conv + k * 1024;
  s16x8 v;
  for (int j = 0; j < 8; ++j) {
    bf16 h = __float2bfloat16(wk[(s * 16 + kq * 8 + j) * 32 + col]);
    short sv;
    __builtin_memcpy(&sv, &h, 2);
    v[j] = sv;
  }
  *reinterpret_cast<s16x8*>(reinterpret_cast<char*>(wpk) + (size_t)t * 16) = v;
}

// ---------------- unary1: h1b = bf16( LN(feats @ w1) )  [N,32] ----------------
__global__ __launch_bounds__(256) void unary1_kernel(const float* __restrict__ feats,
    const float* __restrict__ w1, const float* __restrict__ g1,
    const float* __restrict__ b1, bf16* __restrict__ h1b) {
  __shared__ float sf[8][128];
  __shared__ float sw[128 * 32];
  int tid = threadIdx.x;
  int rbase = blockIdx.x * 8;
  for (int i = tid; i < 1024; i += 256)
    reinterpret_cast<f32x4*>(sw)[i] = reinterpret_cast<const f32x4*>(w1)[i];
  {
    int i = tid;
    int r = rbase + (i >> 5);
    f32x4 v = reinterpret_cast<const f32x4*>(feats)[(size_t)r * 32 + (i & 31)];
    reinterpret_cast<f32x4*>(&sf[0][0])[i] = v;
  }
  __syncthreads();
  int half = tid >> 5;
  int c = tid & 31;
  int r = rbase + half;
  const float* frow = sf[half];
  float acc = 0.f;
  #pragma unroll 8
  for (int kk = 0; kk < 128; ++kk)
    acc += frow[kk] * sw[kk * 32 + c];
  float s = acc, s2 = acc * acc;
  #pragma unroll
  for (int m = 16; m >= 1; m >>= 1) {
    s  += __shfl_xor(s,  m, 64);
    s2 += __shfl_xor(s2, m, 64);
  }
  float mean = s * (1.f / 32.f);
  float var  = s2 * (1.f / 32.f) - mean * mean;
  float y = (acc - mean) * rsqrtf(var + EPS) * g1[c] + b1[c];
  h1b[(size_t)r * 32 + c] = __float2bfloat16(y);
}

// ---------------- conv: h2 = sum_k gather(h1b, nbr[:,k]) @ w_conv[k]  [N,32] f32 ----------------
// Block = 256 thr = 4 waves; block owns one 32-point tile; wave w handles offsets
// [343w/4, 343(w+1)/4); partials reduced via LDS. 3125 blocks -> ~32 waves/CU.
// A-frag: row = lane&31, k-chunk kq=lane>>5; D: col=lane&31, row=(reg&3)+8*(reg>>2)+4*kq
__global__ __launch_bounds__(256) void conv_kernel(const bf16* __restrict__ h1b,
    const int* __restrict__ nbr, const bf16* __restrict__ wpk,
    float* __restrict__ h2) {
  __shared__ float red[4 * 1024];
  int tid = threadIdx.x;
  int wave = tid >> 6;
  int l = tid & 63;
  int col = l & 31;
  int kq = l >> 5;
  int pbase = blockIdx.x * 32;
  const int* nrow = nbr + (size_t)(pbase + col) * KOFF;
  int k0 = (KOFF * wave) >> 2;
  int k1 = (KOFF * (wave + 1)) >> 2;
  f32x16 acc;
  #pragma unroll
  for (int i = 0; i < 16; ++i) acc[i] = 0.f;
  const s16x8* wb = reinterpret_cast<const s16x8*>(wpk);
  const s16x8 zv = {0, 0, 0, 0, 0, 0, 0, 0};
  // 1-deep software pipeline: idx + A-frags prefetched one iteration ahead
  int idx = nrow[k0];
  {
    const s16x8* r = reinterpret_cast<const s16x8*>(h1b + (size_t)(idx < 0 ? 0 : idx) * 32);
    s16x8 a0p = r[kq], a1p = r[2 + kq];
    for (int k = k0; k < k1; ++k) {
      s16x8 ca0 = idx < 0 ? zv : a0p;
      s16x8 ca1 = idx < 0 ? zv : a1p;
      int kn = (k + 1 < k1) ? k + 1 : k0;
      int idxn = nrow[kn];
      const s16x8* rn = reinterpret_cast<const s16x8*>(h1b + (size_t)(idxn < 0 ? 0 : idxn) * 32);
      s16x8 a0n = rn[kq], a1n = rn[2 + kq];
      s16x8 b0 = wb[(size_t)k * 128 + l];
      s16x8 b1 = wb[(size_t)k * 128 + 64 + l];
      acc = __builtin_amdgcn_mfma_f32_32x32x16_bf16(ca0, b0, acc, 0, 0, 0);
      acc = __builtin_amdgcn_mfma_f32_32x32x16_bf16(ca1, b1, acc, 0, 0, 0);
      idx = idxn; a0p = a0n; a1p = a1n;
    }
  }
  #pragma unroll
  for (int reg = 0; reg < 16; ++reg) {
    int rrow = (reg & 3) + 8 * (reg >> 2) + 4 * kq;
    red[wave * 1024 + rrow * 32 + col] = acc[reg];
  }
  __syncthreads();
  const f32x4* rv = reinterpret_cast<const f32x4*>(red);
  f32x4 s = rv[tid] + rv[256 + tid] + rv[512 + tid] + rv[768 + tid];
  reinterpret_cast<f32x4*>(h2 + (size_t)pbase * 32)[tid] = s;
}

// ---------------- unary2: out = gelu(LN(h2 @ w2)) + feats  [N,128] f32 ----------------
__global__ __launch_bounds__(256) void unary2_kernel(const float* __restrict__ h2,
    const float* __restrict__ w2, const float* __restrict__ g2,
    const float* __restrict__ b2, const float* __restrict__ feats,
    float* __restrict__ out) {
  int tid = threadIdx.x;
  int wave = tid >> 6;
  int l = tid & 63;
  int r = blockIdx.x * 4 + wave;
  const float* hrow = h2 + (size_t)r * 32;
  float acc0 = 0.f, acc1 = 0.f;
  #pragma unroll
  for (int q = 0; q < 8; ++q) {
    f32x4 hv = reinterpret_cast<const f32x4*>(hrow)[q];
    #pragma unroll
    for (int j = 0; j < 4; ++j) {
      int kk = q * 4 + j;
      float h = hv[j];
      acc0 += h * w2[kk * 128 + l];
      acc1 += h * w2[kk * 128 + 64 + l];
    }
  }
  float s = acc0 + acc1, s2 = acc0 * acc0 + acc1 * acc1;
  #pragma unroll
  for (int m = 32; m >= 1; m >>= 1) {
    s  += __shfl_xor(s,  m, 64);
    s2 += __shfl_xor(s2, m, 64);
  }
  float mean = s * (1.f / 128.f);
  float var  = s2 * (1.f / 128.f) - mean * mean;
  float inv = rsqrtf(var + EPS);
  float y0 = (acc0 - mean) * inv * g2[l] + b2[l];
  float y1 = (acc1 - mean) * inv * g2[64 + l] + b2[64 + l];
  float ge0 = 0.5f * y0 * (1.f + erff(y0 * 0.70710678118f));
  float ge1 = 0.5f * y1 * (1.f + erff(y1 * 0.70710678118f));
  out[(size_t)r * 128 + l]      = ge0 + feats[(size_t)r * 128 + l];
  out[(size_t)r * 128 + 64 + l] = ge1 + feats[(size_t)r * 128 + 64 + l];
}

extern "C" void kernel_launch(void* const* d_in, const int* in_sizes, int n_in,
                              void* d_out, int out_size, void* d_ws, size_t ws_size,
                              hipStream_t stream) {
  const float* feats  = (const float*)d_in[0];
  const int*   nbr    = (const int*)d_in[1];
  const float* w1     = (const float*)d_in[2];
  const float* ln1_g  = (const float*)d_in[3];
  const float* ln1_b  = (const float*)d_in[4];
  const float* w_conv = (const float*)d_in[5];
  const float* w2     = (const float*)d_in[6];
  const float* ln2_g  = (const float*)d_in[7];
  const float* ln2_b  = (const float*)d_in[8];
  float* out = (float*)d_out;
  char* ws = (char*)d_ws;
  bf16*  h1b = (bf16*)ws;                    // 100000*32*2  = 6,400,000 B
  bf16*  wpk = (bf16*)(ws + 6400000);        // 343*128*16   =   702,464 B
  float* h2  = (float*)(ws + 7102464);       // 100000*32*4  = 12,800,000 B

  hipLaunchKernelGGL(pack_kernel,   dim3((KOFF * 128 + 255) / 256), dim3(256), 0, stream, w_conv, wpk);
  hipLaunchKernelGGL(unary1_kernel, dim3(N_PTS / 8),                dim3(256), 0, stream, feats, w1, ln1_g, ln1_b, h1b);
  hipLaunchKernelGGL(conv_kernel,   dim3(N_PTS / 32),               dim3(256), 0, stream, h1b, nbr, wpk, h2);
  hipLaunchKernelGGL(unary2_kernel, dim3(N_PTS / 4),                dim3(256), 0, stream, h2, w2, ln2_g, ln2_b, feats, out);
}

// Round 3
// 328.486 us; speedup vs baseline: 1.6671x; 1.5435x over previous
//
#include <hip/hip_runtime.h>
#include <hip/hip_bf16.h>

#define N_PTS 100000
#define KOFF 343
#define EPS 1e-5f

typedef __hip_bfloat16 bf16;
typedef __attribute__((ext_vector_type(4))) float f32x4;
typedef __attribute__((ext_vector_type(16))) float f32x16;
typedef __attribute__((ext_vector_type(8))) short s16x8;

// ---------------- pack: w_conv [343][32][32] f32 -> bf16 B-fragments ----------------
// wpk layout: [k][s][lane][j], element = w_conv[k][s*16 + (lane>>5)*8 + j][lane&31]
__global__ __launch_bounds__(256) void pack_kernel(const float* __restrict__ w_conv,
                                                   bf16* __restrict__ wpk) {
  int t = blockIdx.x * 256 + threadIdx.x;
  if (t >= KOFF * 128) return;
  int l = t & 63;
  int s = (t >> 6) & 1;
  int k = t >> 7;
  int col = l & 31;
  int kq = l >> 5;
  const float* wk = w_conv + k * 1024;
  s16x8 v;
  for (int j = 0; j < 8; ++j) {
    bf16 h = __float2bfloat16(wk[(s * 16 + kq * 8 + j) * 32 + col]);
    short sv;
    __builtin_memcpy(&sv, &h, 2);
    v[j] = sv;
  }
  *reinterpret_cast<s16x8*>(reinterpret_cast<char*>(wpk) + (size_t)t * 16) = v;
}

// ---------------- unary1: h1b = bf16( LN(feats @ w1) )  [N,32] ----------------
__global__ __launch_bounds__(256) void unary1_kernel(const float* __restrict__ feats,
    const float* __restrict__ w1, const float* __restrict__ g1,
    const float* __restrict__ b1, bf16* __restrict__ h1b) {
  __shared__ float sf[8][128];
  __shared__ float sw[128 * 32];
  int tid = threadIdx.x;
  int rbase = blockIdx.x * 8;
  for (int i = tid; i < 1024; i += 256)
    reinterpret_cast<f32x4*>(sw)[i] = reinterpret_cast<const f32x4*>(w1)[i];
  {
    int i = tid;
    int r = rbase + (i >> 5);
    f32x4 v = reinterpret_cast<const f32x4*>(feats)[(size_t)r * 32 + (i & 31)];
    reinterpret_cast<f32x4*>(&sf[0][0])[i] = v;
  }
  __syncthreads();
  int half = tid >> 5;
  int c = tid & 31;
  int r = rbase + half;
  const float* frow = sf[half];
  float acc = 0.f;
  #pragma unroll 8
  for (int kk = 0; kk < 128; ++kk)
    acc += frow[kk] * sw[kk * 32 + c];
  float s = acc, s2 = acc * acc;
  #pragma unroll
  for (int m = 16; m >= 1; m >>= 1) {
    s  += __shfl_xor(s,  m, 64);
    s2 += __shfl_xor(s2, m, 64);
  }
  float mean = s * (1.f / 32.f);
  float var  = s2 * (1.f / 32.f) - mean * mean;
  float y = (acc - mean) * rsqrtf(var + EPS) * g1[c] + b1[c];
  h1b[(size_t)r * 32 + c] = __float2bfloat16(y);
}

// ---------------- conv: h2 = sum_k gather(h1b, nbr[:,k]) @ w_conv[k]  [N,32] f32 ----------------
// Block = 256 thr = 4 waves, one 32-point tile. nbr slice (43.9 KB, contiguous in
// global) staged coalesced into LDS (stride 345 -> conflict-free idx reads; buffer
// reused for the f32 reduction). Each wave: ~86 offsets, chunked x4 with all 16
// loads issued before the 8 MFMAs (deep MLP instead of a 2-hop latency chain).
__global__ __launch_bounds__(256) void conv_kernel(const bf16* __restrict__ h1b,
    const int* __restrict__ nbr, const bf16* __restrict__ wpk,
    float* __restrict__ h2) {
  __shared__ int snbr[32 * 345];          // 44,160 B; reused as float red[4096]
  int tid = threadIdx.x;
  int wave = tid >> 6;
  int l = tid & 63;
  int col = l & 31;
  int kq = l >> 5;
  int pbase = blockIdx.x * 32;
  {
    const int* g = nbr + (size_t)pbase * KOFF;   // 32*343 consecutive ints
    for (int i = tid; i < 32 * KOFF; i += 256) {
      unsigned row = (unsigned)i / KOFF;         // magic-mul div
      unsigned kk = (unsigned)i - row * KOFF;
      snbr[row * 345 + kk] = g[i];
    }
  }
  __syncthreads();
  int k0 = (KOFF * wave) >> 2;
  int k1 = (KOFF * (wave + 1)) >> 2;
  f32x16 acc;
  #pragma unroll
  for (int i = 0; i < 16; ++i) acc[i] = 0.f;
  const s16x8* wb = reinterpret_cast<const s16x8*>(wpk);
  const s16x8 zv = {0, 0, 0, 0, 0, 0, 0, 0};
  const int* myrow = snbr + col * 345;
  for (int kb = k0; kb < k1; kb += 4) {
    int id[4];
    s16x8 A0[4], A1[4], B0[4], B1[4];
    #pragma unroll
    for (int j = 0; j < 4; ++j) {
      int k = kb + j;
      id[j] = (k < k1) ? myrow[k] : -1;
    }
    #pragma unroll
    for (int j = 0; j < 4; ++j) {
      int k = kb + j;
      int kc = (k < k1) ? k : (k1 - 1);
      const s16x8* r = reinterpret_cast<const s16x8*>(h1b + (size_t)(id[j] < 0 ? 0 : id[j]) * 32);
      A0[j] = r[kq];
      A1[j] = r[2 + kq];
      B0[j] = wb[(size_t)kc * 128 + l];
      B1[j] = wb[(size_t)kc * 128 + 64 + l];
    }
    #pragma unroll
    for (int j = 0; j < 4; ++j) {
      s16x8 a0 = id[j] < 0 ? zv : A0[j];
      s16x8 a1 = id[j] < 0 ? zv : A1[j];
      acc = __builtin_amdgcn_mfma_f32_32x32x16_bf16(a0, B0[j], acc, 0, 0, 0);
      acc = __builtin_amdgcn_mfma_f32_32x32x16_bf16(a1, B1[j], acc, 0, 0, 0);
    }
  }
  __syncthreads();
  float* red = reinterpret_cast<float*>(snbr);
  #pragma unroll
  for (int reg = 0; reg < 16; ++reg) {
    int rrow = (reg & 3) + 8 * (reg >> 2) + 4 * kq;
    red[wave * 1024 + rrow * 32 + col] = acc[reg];
  }
  __syncthreads();
  const f32x4* rv = reinterpret_cast<const f32x4*>(red);
  f32x4 s = rv[tid] + rv[256 + tid] + rv[512 + tid] + rv[768 + tid];
  reinterpret_cast<f32x4*>(h2 + (size_t)pbase * 32)[tid] = s;
}

// ---------------- unary2: out = gelu(LN(h2 @ w2)) + feats  [N,128] f32 ----------------
__global__ __launch_bounds__(256) void unary2_kernel(const float* __restrict__ h2,
    const float* __restrict__ w2, const float* __restrict__ g2,
    const float* __restrict__ b2, const float* __restrict__ feats,
    float* __restrict__ out) {
  int tid = threadIdx.x;
  int wave = tid >> 6;
  int l = tid & 63;
  int r = blockIdx.x * 4 + wave;
  const float* hrow = h2 + (size_t)r * 32;
  float acc0 = 0.f, acc1 = 0.f;
  #pragma unroll
  for (int q = 0; q < 8; ++q) {
    f32x4 hv = reinterpret_cast<const f32x4*>(hrow)[q];
    #pragma unroll
    for (int j = 0; j < 4; ++j) {
      int kk = q * 4 + j;
      float h = hv[j];
      acc0 += h * w2[kk * 128 + l];
      acc1 += h * w2[kk * 128 + 64 + l];
    }
  }
  float s = acc0 + acc1, s2 = acc0 * acc0 + acc1 * acc1;
  #pragma unroll
  for (int m = 32; m >= 1; m >>= 1) {
    s  += __shfl_xor(s,  m, 64);
    s2 += __shfl_xor(s2, m, 64);
  }
  float mean = s * (1.f / 128.f);
  float var  = s2 * (1.f / 128.f) - mean * mean;
  float inv = rsqrtf(var + EPS);
  float y0 = (acc0 - mean) * inv * g2[l] + b2[l];
  float y1 = (acc1 - mean) * inv * g2[64 + l] + b2[64 + l];
  float ge0 = 0.5f * y0 * (1.f + erff(y0 * 0.70710678118f));
  float ge1 = 0.5f * y1 * (1.f + erff(y1 * 0.70710678118f));
  out[(size_t)r * 128 + l]      = ge0 + feats[(size_t)r * 128 + l];
  out[(size_t)r * 128 + 64 + l] = ge1 + feats[(size_t)r * 128 + 64 + l];
}

extern "C" void kernel_launch(void* const* d_in, const int* in_sizes, int n_in,
                              void* d_out, int out_size, void* d_ws, size_t ws_size,
                              hipStream_t stream) {
  const float* feats  = (const float*)d_in[0];
  const int*   nbr    = (const int*)d_in[1];
  const float* w1     = (const float*)d_in[2];
  const float* ln1_g  = (const float*)d_in[3];
  const float* ln1_b  = (const float*)d_in[4];
  const float* w_conv = (const float*)d_in[5];
  const float* w2     = (const float*)d_in[6];
  const float* ln2_g  = (const float*)d_in[7];
  const float* ln2_b  = (const float*)d_in[8];
  float* out = (float*)d_out;
  char* ws = (char*)d_ws;
  bf16*  h1b = (bf16*)ws;                    // 100000*32*2  = 6,400,000 B
  bf16*  wpk = (bf16*)(ws + 6400000);        // 343*128*16   =   702,464 B
  float* h2  = (float*)(ws + 7102464);       // 100000*32*4  = 12,800,000 B

  hipLaunchKernelGGL(pack_kernel,   dim3((KOFF * 128 + 255) / 256), dim3(256), 0, stream, w_conv, wpk);
  hipLaunchKernelGGL(unary1_kernel, dim3(N_PTS / 8),                dim3(256), 0, stream, feats, w1, ln1_g, ln1_b, h1b);
  hipLaunchKernelGGL(conv_kernel,   dim3(N_PTS / 32),               dim3(256), 0, stream, h1b, nbr, wpk, h2);
  hipLaunchKernelGGL(unary2_kernel, dim3(N_PTS / 4),                dim3(256), 0, stream, h2, w2, ln2_g, ln2_b, feats, out);
}